// Round 1
// baseline (222.169 us; speedup 1.0000x reference)
//
#include <hip/hip_runtime.h>
#include <cmath>

#define BSZ 32
#define NMEL 80
#define TMEL 800
#define NLAYERS 6
#define NHEADS 4
#define TTEXT 160
#define POS_WEIGHT 5.0f
#define GUIDE_K 3.125f

// ws layout (doubles): [0]=l1_a, [1]=l1_b, [2]=bce, [3]=guide

__device__ __forceinline__ void wave_atomic_add(float v, double* dst) {
#pragma unroll
    for (int off = 32; off; off >>= 1) v += __shfl_xor(v, off, 64);
    if ((threadIdx.x & 63) == 0) atomicAdd(dst, (double)v);
}

// ---------------- mel L1 (masked) ----------------
__global__ void mel_kernel(const float4* __restrict__ mo,
                           const float4* __restrict__ mop,
                           const float4* __restrict__ mt,
                           const int* __restrict__ mel_len,
                           double* __restrict__ ws) {
    const int T4 = TMEL / 4;                 // 200
    const int total = BSZ * NMEL * T4;       // 512000
    float s_a = 0.f, s_b = 0.f;
    for (int idx = blockIdx.x * blockDim.x + threadIdx.x; idx < total;
         idx += gridDim.x * blockDim.x) {
        int t4 = idx % T4;
        int b  = idx / (NMEL * T4);
        int ml = mel_len[b];
        int t0 = t4 * 4;
        if (t0 >= ml) continue;              // whole vec masked out
        float4 a = mo[idx];
        float4 p = mop[idx];
        float4 g = mt[idx];
        float m0 = (t0 + 0 < ml) ? 1.f : 0.f;
        float m1 = (t0 + 1 < ml) ? 1.f : 0.f;
        float m2 = (t0 + 2 < ml) ? 1.f : 0.f;
        float m3 = (t0 + 3 < ml) ? 1.f : 0.f;
        s_a += fabsf(a.x - g.x) * m0 + fabsf(a.y - g.y) * m1 +
               fabsf(a.z - g.z) * m2 + fabsf(a.w - g.w) * m3;
        s_b += fabsf(p.x - g.x) * m0 + fabsf(p.y - g.y) * m1 +
               fabsf(p.z - g.z) * m2 + fabsf(p.w - g.w) * m3;
    }
    wave_atomic_add(s_a, ws + 0);
    wave_atomic_add(s_b, ws + 1);
}

// ---------------- guide loss ----------------
// domain: (b, t, l4) over the slice layers {4,5} x heads {0,1}
__global__ void guide_kernel(const float* __restrict__ A,
                             const int* __restrict__ mel_len,
                             const int* __restrict__ text_len,
                             double* __restrict__ ws) {
    const int L4 = TTEXT / 4;                // 40
    const int total = BSZ * TMEL * L4;       // 1,024,000
    const long long bstride = (long long)NLAYERS * NHEADS * TMEL * TTEXT; // 3,072,000
    const long long lstride = (long long)NHEADS * TMEL * TTEXT;           //   512,000
    const long long hstride = (long long)TMEL * TTEXT;                    //   128,000
    float s = 0.f;
    for (int idx = blockIdx.x * blockDim.x + threadIdx.x; idx < total;
         idx += gridDim.x * blockDim.x) {
        int l4 = idx % L4;
        int t  = (idx / L4) % TMEL;
        int b  = idx / (L4 * TMEL);
        int ml = mel_len[b];
        int tl = text_len[b];
        int l0 = l4 * 4;
        if (t >= ml || l0 >= tl) continue;   // gmask zero for whole vec
        float inv_ml = 1.f / (float)ml;
        float inv_tl = 1.f / (float)tl;
        float tn = (float)t * inv_ml;
        long long off = (long long)b * bstride + 4 * lstride +
                        (long long)t * TTEXT + l0;
        const float4 a0 = *(const float4*)(A + off);                       // L4 H0
        const float4 a1 = *(const float4*)(A + off + hstride);             // L4 H1
        const float4 a2 = *(const float4*)(A + off + lstride);             // L5 H0
        const float4 a3 = *(const float4*)(A + off + lstride + hstride);   // L5 H1
        const float asum[4] = {a0.x + a1.x + a2.x + a3.x,
                               a0.y + a1.y + a2.y + a3.y,
                               a0.z + a1.z + a2.z + a3.z,
                               a0.w + a1.w + a2.w + a3.w};
#pragma unroll
        for (int j = 0; j < 4; ++j) {
            int l = l0 + j;
            if (l < tl) {
                float d = tn - (float)l * inv_tl;
                float w = 1.f - __expf(-GUIDE_K * d * d);
                s += w * asum[j];
            }
        }
    }
    wave_atomic_add(s, ws + 3);
}

// ---------------- gate BCE ----------------
__device__ __forceinline__ float softplus_f(float v) {
    return fmaxf(v, 0.f) + log1pf(expf(-fabsf(v)));
}

__global__ void gate_kernel(const float* __restrict__ x,
                            const float* __restrict__ y,
                            const int* __restrict__ mel_len,
                            double* __restrict__ ws) {
    const int total = BSZ * TMEL;            // 25600
    float s = 0.f;
    for (int idx = blockIdx.x * blockDim.x + threadIdx.x; idx < total;
         idx += gridDim.x * blockDim.x) {
        int t = idx % TMEL;
        int b = idx / TMEL;
        if (t >= mel_len[b]) continue;
        float xv = x[idx], yv = y[idx];
        s += POS_WEIGHT * yv * softplus_f(-xv) + (1.f - yv) * softplus_f(xv);
    }
    wave_atomic_add(s, ws + 2);
}

// ---------------- finalize ----------------
__global__ void finalize_kernel(const double* __restrict__ ws,
                                const int* __restrict__ mel_len,
                                const int* __restrict__ text_len,
                                float* __restrict__ out) {
    if (threadIdx.x == 0 && blockIdx.x == 0) {
        double nv = 0.0, gsum = 0.0;
        for (int b = 0; b < BSZ; ++b) {
            int ml = min(mel_len[b], TMEL);
            int tl = min(text_len[b], TTEXT);
            nv += (double)ml;
            gsum += (double)ml * (double)tl;
        }
        double n_mel = nv * (double)NMEL;
        out[0] = (float)((ws[0] + ws[1]) / n_mel);
        out[1] = (float)(ws[2] / nv);
        out[2] = (float)(ws[3] / (4.0 * gsum));
    }
}

extern "C" void kernel_launch(void* const* d_in, const int* in_sizes, int n_in,
                              void* d_out, int out_size, void* d_ws, size_t ws_size,
                              hipStream_t stream) {
    const float* mel_out      = (const float*)d_in[0];
    const float* mel_out_post = (const float*)d_in[1];
    const float* gate_out     = (const float*)d_in[2];
    const float* mel_target   = (const float*)d_in[3];
    const float* gate_target  = (const float*)d_in[4];
    const float* alignments   = (const float*)d_in[5];
    const int*   text_lengths = (const int*)d_in[6];
    const int*   mel_lengths  = (const int*)d_in[7];
    double* acc = (double*)d_ws;
    float*  out = (float*)d_out;

    hipMemsetAsync(acc, 0, 4 * sizeof(double), stream);

    mel_kernel<<<1024, 256, 0, stream>>>((const float4*)mel_out,
                                         (const float4*)mel_out_post,
                                         (const float4*)mel_target,
                                         mel_lengths, acc);
    guide_kernel<<<2048, 256, 0, stream>>>(alignments, mel_lengths,
                                           text_lengths, acc);
    gate_kernel<<<100, 256, 0, stream>>>(gate_out, gate_target,
                                         mel_lengths, acc);
    finalize_kernel<<<1, 64, 0, stream>>>(acc, mel_lengths, text_lengths, out);
}

// Round 2
// 29.934 us; speedup vs baseline: 7.4219x; 7.4219x over previous
//
#include <hip/hip_runtime.h>
#include <cmath>

#define BSZ 32
#define NMEL 80
#define TMEL 800
#define NLAYERS 6
#define NHEADS 4
#define TTEXT 160
#define POS_WEIGHT 5.0f
#define GUIDE_K 3.125f

#define MEL_BLOCKS 1024
#define GUIDE_BLOCKS 2048
#define GATE_BLOCKS 100

// ws layout (floats):
// [0, 2048)            guide partials
// [2048, 3072)         mel_a partials
// [3072, 4096)         mel_b partials
// [4096, 4196)         gate partials
#define WS_GUIDE 0
#define WS_MELA  (WS_GUIDE + GUIDE_BLOCKS)
#define WS_MELB  (WS_MELA + MEL_BLOCKS)
#define WS_GATE  (WS_MELB + MEL_BLOCKS)

// block = 256 threads = 4 waves. Returns full sum in thread 0 only.
__device__ __forceinline__ float block_reduce_256(float v, float* lds) {
#pragma unroll
    for (int off = 32; off; off >>= 1) v += __shfl_xor(v, off, 64);
    if ((threadIdx.x & 63) == 0) lds[threadIdx.x >> 6] = v;
    __syncthreads();
    float r = 0.f;
    if (threadIdx.x == 0) r = lds[0] + lds[1] + lds[2] + lds[3];
    __syncthreads();   // lds reusable after this
    return r;
}

// ---------------- mel L1 (masked) ----------------
__global__ void mel_kernel(const float4* __restrict__ mo,
                           const float4* __restrict__ mop,
                           const float4* __restrict__ mt,
                           const int* __restrict__ mel_len,
                           float* __restrict__ ws) {
    __shared__ float lds[4];
    const int T4 = TMEL / 4;                 // 200
    const int total = BSZ * NMEL * T4;       // 512000
    float s_a = 0.f, s_b = 0.f;
    for (int idx = blockIdx.x * blockDim.x + threadIdx.x; idx < total;
         idx += gridDim.x * blockDim.x) {
        int t4 = idx % T4;
        int b  = idx / (NMEL * T4);
        int ml = mel_len[b];
        int t0 = t4 * 4;
        if (t0 >= ml) continue;              // whole vec masked out
        float4 a = mo[idx];
        float4 p = mop[idx];
        float4 g = mt[idx];
        float m0 = (t0 + 0 < ml) ? 1.f : 0.f;
        float m1 = (t0 + 1 < ml) ? 1.f : 0.f;
        float m2 = (t0 + 2 < ml) ? 1.f : 0.f;
        float m3 = (t0 + 3 < ml) ? 1.f : 0.f;
        s_a += fabsf(a.x - g.x) * m0 + fabsf(a.y - g.y) * m1 +
               fabsf(a.z - g.z) * m2 + fabsf(a.w - g.w) * m3;
        s_b += fabsf(p.x - g.x) * m0 + fabsf(p.y - g.y) * m1 +
               fabsf(p.z - g.z) * m2 + fabsf(p.w - g.w) * m3;
    }
    float ra = block_reduce_256(s_a, lds);
    float rb = block_reduce_256(s_b, lds);
    if (threadIdx.x == 0) {
        ws[WS_MELA + blockIdx.x] = ra;
        ws[WS_MELB + blockIdx.x] = rb;
    }
}

// ---------------- guide loss ----------------
// domain: (b, t, l4) over the slice layers {4,5} x heads {0,1}
__global__ void guide_kernel(const float* __restrict__ A,
                             const int* __restrict__ mel_len,
                             const int* __restrict__ text_len,
                             float* __restrict__ ws) {
    __shared__ float lds[4];
    const int L4 = TTEXT / 4;                // 40
    const int total = BSZ * TMEL * L4;       // 1,024,000
    const long long bstride = (long long)NLAYERS * NHEADS * TMEL * TTEXT; // 3,072,000
    const long long lstride = (long long)NHEADS * TMEL * TTEXT;           //   512,000
    const long long hstride = (long long)TMEL * TTEXT;                    //   128,000
    float s = 0.f;
    for (int idx = blockIdx.x * blockDim.x + threadIdx.x; idx < total;
         idx += gridDim.x * blockDim.x) {
        int l4 = idx % L4;
        int t  = (idx / L4) % TMEL;
        int b  = idx / (L4 * TMEL);
        int ml = mel_len[b];
        int tl = text_len[b];
        int l0 = l4 * 4;
        if (t >= ml || l0 >= tl) continue;   // gmask zero for whole vec
        float inv_ml = 1.f / (float)ml;
        float inv_tl = 1.f / (float)tl;
        float tn = (float)t * inv_ml;
        long long off = (long long)b * bstride + 4 * lstride +
                        (long long)t * TTEXT + l0;
        const float4 a0 = *(const float4*)(A + off);                       // L4 H0
        const float4 a1 = *(const float4*)(A + off + hstride);             // L4 H1
        const float4 a2 = *(const float4*)(A + off + lstride);             // L5 H0
        const float4 a3 = *(const float4*)(A + off + lstride + hstride);   // L5 H1
        const float asum[4] = {a0.x + a1.x + a2.x + a3.x,
                               a0.y + a1.y + a2.y + a3.y,
                               a0.z + a1.z + a2.z + a3.z,
                               a0.w + a1.w + a2.w + a3.w};
#pragma unroll
        for (int j = 0; j < 4; ++j) {
            int l = l0 + j;
            if (l < tl) {
                float d = tn - (float)l * inv_tl;
                float w = 1.f - __expf(-GUIDE_K * d * d);
                s += w * asum[j];
            }
        }
    }
    float r = block_reduce_256(s, lds);
    if (threadIdx.x == 0) ws[WS_GUIDE + blockIdx.x] = r;
}

// ---------------- gate BCE ----------------
__device__ __forceinline__ float softplus_f(float v) {
    return fmaxf(v, 0.f) + log1pf(expf(-fabsf(v)));
}

__global__ void gate_kernel(const float* __restrict__ x,
                            const float* __restrict__ y,
                            const int* __restrict__ mel_len,
                            float* __restrict__ ws) {
    __shared__ float lds[4];
    const int total = BSZ * TMEL;            // 25600
    float s = 0.f;
    for (int idx = blockIdx.x * blockDim.x + threadIdx.x; idx < total;
         idx += gridDim.x * blockDim.x) {
        int t = idx % TMEL;
        int b = idx / TMEL;
        if (t >= mel_len[b]) continue;
        float xv = x[idx], yv = y[idx];
        s += POS_WEIGHT * yv * softplus_f(-xv) + (1.f - yv) * softplus_f(xv);
    }
    float r = block_reduce_256(s, lds);
    if (threadIdx.x == 0) ws[WS_GATE + blockIdx.x] = r;
}

// ---------------- finalize: reduce partials + quotients ----------------
__global__ void finalize_kernel(const float* __restrict__ ws,
                                const int* __restrict__ mel_len,
                                const int* __restrict__ text_len,
                                float* __restrict__ out) {
    __shared__ float lds[4];
    float sg = 0.f, sa = 0.f, sb = 0.f, sgt = 0.f;
    for (int i = threadIdx.x; i < GUIDE_BLOCKS; i += 256) sg += ws[WS_GUIDE + i];
    for (int i = threadIdx.x; i < MEL_BLOCKS; i += 256) {
        sa += ws[WS_MELA + i];
        sb += ws[WS_MELB + i];
    }
    for (int i = threadIdx.x; i < GATE_BLOCKS; i += 256) sgt += ws[WS_GATE + i];
    float rg  = block_reduce_256(sg, lds);
    float ra  = block_reduce_256(sa, lds);
    float rb  = block_reduce_256(sb, lds);
    float rgt = block_reduce_256(sgt, lds);
    if (threadIdx.x == 0) {
        double nv = 0.0, gsum = 0.0;
        for (int b = 0; b < BSZ; ++b) {
            int ml = min(mel_len[b], TMEL);
            int tl = min(text_len[b], TTEXT);
            nv += (double)ml;
            gsum += (double)ml * (double)tl;
        }
        double n_mel = nv * (double)NMEL;
        out[0] = (float)(((double)ra + (double)rb) / n_mel);
        out[1] = (float)((double)rgt / nv);
        out[2] = (float)((double)rg / (4.0 * gsum));
    }
}

extern "C" void kernel_launch(void* const* d_in, const int* in_sizes, int n_in,
                              void* d_out, int out_size, void* d_ws, size_t ws_size,
                              hipStream_t stream) {
    const float* mel_out      = (const float*)d_in[0];
    const float* mel_out_post = (const float*)d_in[1];
    const float* gate_out     = (const float*)d_in[2];
    const float* mel_target   = (const float*)d_in[3];
    const float* gate_target  = (const float*)d_in[4];
    const float* alignments   = (const float*)d_in[5];
    const int*   text_lengths = (const int*)d_in[6];
    const int*   mel_lengths  = (const int*)d_in[7];
    float* ws  = (float*)d_ws;
    float* out = (float*)d_out;

    mel_kernel<<<MEL_BLOCKS, 256, 0, stream>>>((const float4*)mel_out,
                                               (const float4*)mel_out_post,
                                               (const float4*)mel_target,
                                               mel_lengths, ws);
    guide_kernel<<<GUIDE_BLOCKS, 256, 0, stream>>>(alignments, mel_lengths,
                                                   text_lengths, ws);
    gate_kernel<<<GATE_BLOCKS, 256, 0, stream>>>(gate_out, gate_target,
                                                 mel_lengths, ws);
    finalize_kernel<<<1, 256, 0, stream>>>(ws, mel_lengths, text_lengths, out);
}

// Round 3
// 23.349 us; speedup vs baseline: 9.5150x; 1.2820x over previous
//
#include <hip/hip_runtime.h>
#include <cmath>

#define BSZ 32
#define NMEL 80
#define TMEL 800
#define NLAYERS 6
#define NHEADS 4
#define TTEXT 160
#define POS_WEIGHT 5.0f
#define GUIDE_K 3.125f

// block-role segmentation of a single fused kernel
#define GUIDE_B 1400
#define MEL_B   640
#define GATE_B  8
#define TOTAL_B (GUIDE_B + MEL_B + GATE_B)   // 2048 blocks x 4 waves = full residency

// ws layout (floats):
// [0, GUIDE_B)                       guide partials
// [GUIDE_B, GUIDE_B+MEL_B)           mel_a partials
// [GUIDE_B+MEL_B, GUIDE_B+2*MEL_B)   mel_b partials
// [GUIDE_B+2*MEL_B, +GATE_B)         gate partials
#define WS_GUIDE 0
#define WS_MELA  (WS_GUIDE + GUIDE_B)
#define WS_MELB  (WS_MELA + MEL_B)
#define WS_GATE  (WS_MELB + MEL_B)

// block = 256 threads = 4 waves. Full sum returned in thread 0.
__device__ __forceinline__ float block_reduce_256(float v, float* lds) {
#pragma unroll
    for (int off = 32; off; off >>= 1) v += __shfl_xor(v, off, 64);
    if ((threadIdx.x & 63) == 0) lds[threadIdx.x >> 6] = v;
    __syncthreads();
    float r = 0.f;
    if (threadIdx.x == 0) r = lds[0] + lds[1] + lds[2] + lds[3];
    __syncthreads();
    return r;
}

__device__ __forceinline__ float softplus_f(float v) {
    return fmaxf(v, 0.f) + log1pf(expf(-fabsf(v)));
}

__global__ void fused_kernel(const float4* __restrict__ mo,
                             const float4* __restrict__ mop,
                             const float4* __restrict__ mt,
                             const float* __restrict__ A,
                             const float4* __restrict__ gx,
                             const float4* __restrict__ gy,
                             const int* __restrict__ mel_len,
                             const int* __restrict__ text_len,
                             float* __restrict__ ws) {
    __shared__ float lds[4];
    const int bid = blockIdx.x;

    if (bid < GUIDE_B) {
        // ---------------- guide loss ----------------
        const int L4 = TTEXT / 4;                 // 40
        const int total = BSZ * TMEL * L4;        // 1,024,000
        const long long bstride = (long long)NLAYERS * NHEADS * TMEL * TTEXT;
        const long long lstride = (long long)NHEADS * TMEL * TTEXT;
        const long long hstride = (long long)TMEL * TTEXT;
        float s = 0.f;
        for (int idx = bid * 256 + threadIdx.x; idx < total; idx += GUIDE_B * 256) {
            int l4 = idx % L4;
            int t  = (idx / L4) % TMEL;
            int b  = idx / (L4 * TMEL);
            int ml = mel_len[b];
            int tl = text_len[b];
            int l0 = l4 * 4;
            if (t >= ml || l0 >= tl) continue;
            float inv_ml = 1.f / (float)ml;
            float inv_tl = 1.f / (float)tl;
            float tn = (float)t * inv_ml;
            long long off = (long long)b * bstride + 4 * lstride +
                            (long long)t * TTEXT + l0;
            const float4 a0 = *(const float4*)(A + off);
            const float4 a1 = *(const float4*)(A + off + hstride);
            const float4 a2 = *(const float4*)(A + off + lstride);
            const float4 a3 = *(const float4*)(A + off + lstride + hstride);
            const float asum[4] = {a0.x + a1.x + a2.x + a3.x,
                                   a0.y + a1.y + a2.y + a3.y,
                                   a0.z + a1.z + a2.z + a3.z,
                                   a0.w + a1.w + a2.w + a3.w};
#pragma unroll
            for (int j = 0; j < 4; ++j) {
                int l = l0 + j;
                if (l < tl) {
                    float d = tn - (float)l * inv_tl;
                    float w = 1.f - __expf(-GUIDE_K * d * d);
                    s += w * asum[j];
                }
            }
        }
        float r = block_reduce_256(s, lds);
        if (threadIdx.x == 0) ws[WS_GUIDE + bid] = r;
    } else if (bid < GUIDE_B + MEL_B) {
        // ---------------- mel L1 (masked) ----------------
        const int mb = bid - GUIDE_B;
        const int T4 = TMEL / 4;                  // 200
        const int total = BSZ * NMEL * T4;        // 512000
        float s_a = 0.f, s_b = 0.f;
        for (int idx = mb * 256 + threadIdx.x; idx < total; idx += MEL_B * 256) {
            int t4 = idx % T4;
            int b  = idx / (NMEL * T4);
            int ml = mel_len[b];
            int t0 = t4 * 4;
            if (t0 >= ml) continue;
            float4 a = mo[idx];
            float4 p = mop[idx];
            float4 g = mt[idx];
            float m0 = (t0 + 0 < ml) ? 1.f : 0.f;
            float m1 = (t0 + 1 < ml) ? 1.f : 0.f;
            float m2 = (t0 + 2 < ml) ? 1.f : 0.f;
            float m3 = (t0 + 3 < ml) ? 1.f : 0.f;
            s_a += fabsf(a.x - g.x) * m0 + fabsf(a.y - g.y) * m1 +
                   fabsf(a.z - g.z) * m2 + fabsf(a.w - g.w) * m3;
            s_b += fabsf(p.x - g.x) * m0 + fabsf(p.y - g.y) * m1 +
                   fabsf(p.z - g.z) * m2 + fabsf(p.w - g.w) * m3;
        }
        float ra = block_reduce_256(s_a, lds);
        float rb = block_reduce_256(s_b, lds);
        if (threadIdx.x == 0) {
            ws[WS_MELA + mb] = ra;
            ws[WS_MELB + mb] = rb;
        }
    } else {
        // ---------------- gate BCE ----------------
        const int gb = bid - GUIDE_B - MEL_B;
        const int T4 = TMEL / 4;                  // 200
        const int total = BSZ * T4;               // 6400 vec4 items
        float s = 0.f;
        for (int idx = gb * 256 + threadIdx.x; idx < total; idx += GATE_B * 256) {
            int t4 = idx % T4;
            int b  = idx / T4;
            int ml = mel_len[b];
            int t0 = t4 * 4;
            if (t0 >= ml) continue;
            float4 xv = gx[idx];
            float4 yv = gy[idx];
            float e[4] = {
                POS_WEIGHT * yv.x * softplus_f(-xv.x) + (1.f - yv.x) * softplus_f(xv.x),
                POS_WEIGHT * yv.y * softplus_f(-xv.y) + (1.f - yv.y) * softplus_f(xv.y),
                POS_WEIGHT * yv.z * softplus_f(-xv.z) + (1.f - yv.z) * softplus_f(xv.z),
                POS_WEIGHT * yv.w * softplus_f(-xv.w) + (1.f - yv.w) * softplus_f(xv.w)};
#pragma unroll
            for (int j = 0; j < 4; ++j)
                if (t0 + j < ml) s += e[j];
        }
        float r = block_reduce_256(s, lds);
        if (threadIdx.x == 0) ws[WS_GATE + gb] = r;
    }
}

// ---------------- finalize: reduce partials + quotients ----------------
__global__ void finalize_kernel(const float* __restrict__ ws,
                                const int* __restrict__ mel_len,
                                const int* __restrict__ text_len,
                                float* __restrict__ out) {
    __shared__ float lds[4];
    float sg = 0.f, sa = 0.f, sb = 0.f, sgt = 0.f;
    for (int i = threadIdx.x; i < GUIDE_B; i += 256) sg += ws[WS_GUIDE + i];
    for (int i = threadIdx.x; i < MEL_B; i += 256) {
        sa += ws[WS_MELA + i];
        sb += ws[WS_MELB + i];
    }
    if (threadIdx.x < GATE_B) sgt = ws[WS_GATE + threadIdx.x];
    float rg  = block_reduce_256(sg, lds);
    float ra  = block_reduce_256(sa, lds);
    float rb  = block_reduce_256(sb, lds);
    float rgt = block_reduce_256(sgt, lds);
    if (threadIdx.x == 0) {
        double nv = 0.0, gsum = 0.0;
        for (int b = 0; b < BSZ; ++b) {
            int ml = min(mel_len[b], TMEL);
            int tl = min(text_len[b], TTEXT);
            nv += (double)ml;
            gsum += (double)ml * (double)tl;
        }
        double n_mel = nv * (double)NMEL;
        out[0] = (float)(((double)ra + (double)rb) / n_mel);
        out[1] = (float)((double)rgt / nv);
        out[2] = (float)((double)rg / (4.0 * gsum));
    }
}

extern "C" void kernel_launch(void* const* d_in, const int* in_sizes, int n_in,
                              void* d_out, int out_size, void* d_ws, size_t ws_size,
                              hipStream_t stream) {
    const float* mel_out      = (const float*)d_in[0];
    const float* mel_out_post = (const float*)d_in[1];
    const float* gate_out     = (const float*)d_in[2];
    const float* mel_target   = (const float*)d_in[3];
    const float* gate_target  = (const float*)d_in[4];
    const float* alignments   = (const float*)d_in[5];
    const int*   text_lengths = (const int*)d_in[6];
    const int*   mel_lengths  = (const int*)d_in[7];
    float* ws  = (float*)d_ws;
    float* out = (float*)d_out;

    fused_kernel<<<TOTAL_B, 256, 0, stream>>>((const float4*)mel_out,
                                              (const float4*)mel_out_post,
                                              (const float4*)mel_target,
                                              alignments,
                                              (const float4*)gate_out,
                                              (const float4*)gate_target,
                                              mel_lengths, text_lengths, ws);
    finalize_kernel<<<1, 256, 0, stream>>>(ws, mel_lengths, text_lengths, out);
}